// Round 12
// baseline (151.929 us; speedup 1.0000x reference)
//
#include <hip/hip_runtime.h>
#include <math.h>

#define SEQLEN   2048
#define HIDDEN   1024
#define NMODES   32
#define CHANNELS 4096
#define NCH      32      // chunks
#define CL       64      // chunk length
#define NST      31      // stored carry slots (chunks 0..30)
#define VP       72      // padded LDS row stride in bf16 (144 B: 16B-aligned rows)

typedef float  f2    __attribute__((ext_vector_type(2)));
typedef short  s8v   __attribute__((ext_vector_type(8)));
typedef float  f32x4 __attribute__((ext_vector_type(4)));

union Frag { s8v s; unsigned u[4]; };

// ---- small helpers -------------------------------------------------------
__device__ __forceinline__ f2 pk_fma(f2 a, f2 b, f2 c) {
    f2 d; asm("v_pk_fma_f32 %0, %1, %2, %3" : "=v"(d) : "v"(a), "v"(b), "v"(c)); return d;
}
template <int CTRL>
__device__ __forceinline__ float dpp_add(float p) {
    int t = __builtin_amdgcn_update_dpp(0, __float_as_int(p), CTRL, 0xF, 0xF, true);
    return p + __int_as_float(t);
}
// proven 32-lane sum (R2): result lands in lanes 16..31 (and 48..63)
__device__ __forceinline__ float sum32_to16(float p) {
    p = dpp_add<0xB1>(p);    // quad xor1
    p = dpp_add<0x4E>(p);    // quad xor2
    p = dpp_add<0x124>(p);   // row_ror:4
    p = dpp_add<0x128>(p);   // row_ror:8
    p = dpp_add<0x142>(p);   // row_bcast15 -> upper row holds 32-sum
    return p;
}
__device__ __forceinline__ unsigned cvt_pk_bf16(float lo, float hi) {
    unsigned d;
    asm("v_cvt_pk_bf16_f32 %0, %1, %2" : "=v"(d) : "v"(lo), "v"(hi));
    return d;
}
__device__ __forceinline__ short bf16of(float x) {
    return (short)(cvt_pk_bf16(x, x) & 0xffffu);
}

// A_disc only (bilinear, alpha=0.5)
__device__ __forceinline__ void mode_A(float dt, float al, float aim,
                                       float& adr, float& adi)
{
    const float hd = 0.5f * dt;
    const float ar = -expf(al);
    const float dr = 1.0f - hd * ar, di = -hd * aim;
    const float inv = 1.0f / (dr * dr + di * di);
    const float nr = 1.0f + hd * ar, ni = hd * aim;
    adr = (nr * dr + ni * di) * inv;
    adi = (ni * dr - nr * di) * inv;
}

// one mode: A_disc and B' = Cc .* B_disc (C folded, v-space)
__device__ __forceinline__ void coef1(
    const float* __restrict__ log_dt, const float* __restrict__ A_log,
    const float* __restrict__ A_imag, const float* __restrict__ Bp,
    const float* __restrict__ Cp, int h, int m,
    float& adr, float& adi, float& bpr, float& bpi)
{
    const int idx = h * NMODES + m;
    const float dt = expf(log_dt[h]);
    const float hd = 0.5f * dt;
    const float ar = -expf(A_log[idx]);
    const float ai = A_imag[idx];
    const float dr = 1.f - hd * ar, di = -hd * ai;
    const float inv = 1.f / (dr * dr + di * di);
    const float nr = 1.f + hd * ar, ni = hd * ai;
    adr = (nr * dr + ni * di) * inv;
    adi = (ni * dr - nr * di) * inv;
    const float tbr = dt * Bp[idx * 2], tbi = dt * Bp[idx * 2 + 1];
    const float bdr = (tbr * dr + tbi * di) * inv;
    const float bdi = (tbi * dr - tbr * di) * inv;
    const float cr = 2.f * Cp[idx * 2], ci = 2.f * Cp[idx * 2 + 1];
    bpr = cr * bdr - ci * bdi;
    bpi = cr * bdi + ci * bdr;
}

// ---- Kernel 1: local chunk end states via MFMA  Xend = V x U -------------
// Block = 256 thr = 4 waves = 4 channels. One wave per channel.
__global__ __launch_bounds__(256) void ssm_states_mfma(
    const float* __restrict__ input, const float* __restrict__ log_dt,
    const float* __restrict__ A_log, const float* __restrict__ A_imag,
    const float* __restrict__ Bp, const float* __restrict__ Cp,
    float* __restrict__ states)          // [ch][31][64] planar re[32]|im[32]
{
    __shared__ __align__(16) short Vs[4][64 * VP];
    const int tid = threadIdx.x, wv = tid >> 6, l = tid & 63;
    const int g = blockIdx.x;
    const int ch = ((((g & 7) << 7) | (g >> 3)) << 2) + wv;   // XCD-grouped
    const int h = ch & (HIDDEN - 1), b = ch >> 10;
    const int ml = l & 31;
    const int lr = l & 15, lk = (l >> 4) * 8, lo = (l >> 4) * 4;

    const float* ub = input + (size_t)b * SEQLEN * HIDDEN + h;

    // issue the 32 u loads early; latency hides under the V build
    float uf[32];
    #pragma unroll
    for (int nt = 0; nt < 2; ++nt)
      #pragma unroll
      for (int ks = 0; ks < 2; ++ks) {
        const int base = (nt * 2 + ks) * 8;
        const int n  = nt * 16 + lr;
        const int k0 = ks * 32 + lk;
        #pragma unroll
        for (int j = 0; j < 8; ++j)
            uf[base + j] = ub[(size_t)(n * CL + k0 + j) * HIDDEN];
      }

    float adr, adi, bpr, bpi;
    coef1(log_dt, A_log, A_imag, Bp, Cp, h, ml, adr, adi, bpr, bpi);

    // build V: V[m][s] = Re(A^{63-s} B'), V[32+m][s] = Im(...)
    short* V = Vs[wv];
    {
        float wr = bpr, wi = bpi;
        for (int s = CL - 1; s >= 0; --s) {
            if (l < 32) {
                V[ml * VP + s]        = bf16of(wr);
                V[(32 + ml) * VP + s] = bf16of(wi);
            }
            const float nwr = adr * wr - adi * wi;
            const float nwi = adr * wi + adi * wr;
            wr = nwr; wi = nwi;
        }
    }

    // U B-frags (bf16)
    Frag UB[2][2];
    #pragma unroll
    for (int nt = 0; nt < 2; ++nt)
      #pragma unroll
      for (int ks = 0; ks < 2; ++ks) {
        const int base = (nt * 2 + ks) * 8;
        #pragma unroll
        for (int q = 0; q < 4; ++q)
            UB[nt][ks].u[q] = cvt_pk_bf16(uf[base + 2 * q], uf[base + 2 * q + 1]);
      }

    // V A-frags + 16 MFMAs
    f32x4 acc[4][2];
    #pragma unroll
    for (int mt = 0; mt < 4; ++mt)
      #pragma unroll
      for (int nt = 0; nt < 2; ++nt) { f32x4 z = {0.f, 0.f, 0.f, 0.f}; acc[mt][nt] = z; }
    #pragma unroll
    for (int ks = 0; ks < 2; ++ks) {
        Frag VA[4];
        #pragma unroll
        for (int mt = 0; mt < 4; ++mt)
            VA[mt].s = *(const s8v*)(V + (16 * mt + lr) * VP + ks * 32 + lk);
        #pragma unroll
        for (int mt = 0; mt < 4; ++mt)
          #pragma unroll
          for (int nt = 0; nt < 2; ++nt)
            acc[mt][nt] = __builtin_amdgcn_mfma_f32_16x16x32_bf16(
                VA[mt].s, UB[nt][ks].s, acc[mt][nt], 0, 0, 0);
    }

    // store local end states (skip chunk 31)
    float* sb = states + (size_t)ch * NST * 64;
    #pragma unroll
    for (int mt = 0; mt < 4; ++mt)
      #pragma unroll
      for (int nt = 0; nt < 2; ++nt) {
        const int n = nt * 16 + lr;
        if (n < NST) {
          #pragma unroll
          for (int r = 0; r < 4; ++r)
            sb[(size_t)n * 64 + 16 * mt + lo + r] = acc[mt][nt][r];
        }
      }
}

// ---- Kernel 2 (tiny): in-place serial prefix over chunk states -----------
// After: slot c = true v-state at end of chunk c (carry into c+1).
__global__ void ssm_combine(
    const float* __restrict__ log_dt, const float* __restrict__ A_log,
    const float* __restrict__ A_imag, float* __restrict__ states)
{
    const int gid = blockIdx.x * 256 + threadIdx.x;
    const int ch  = gid >> 2;
    const int ll  = gid & 3;
    const int h   = ch & (HIDDEN - 1);
    const int m0  = ll * 8;

    f2 Pr[4], Pi[4], nPi[4];
    {
        float adr[8], adi[8];
        const float dt = expf(log_dt[h]);
        const float* alp = A_log  + (size_t)h * NMODES + m0;
        const float* amp = A_imag + (size_t)h * NMODES + m0;
        #pragma unroll
        for (int k = 0; k < 8; ++k) mode_A(dt, alp[k], amp[k], adr[k], adi[k]);
        #pragma unroll
        for (int p = 0; p < 4; ++p) { Pr[p] = f2{adr[2*p], adr[2*p+1]}; Pi[p] = f2{adi[2*p], adi[2*p+1]}; }
        #pragma unroll
        for (int s = 0; s < 6; ++s) {            // A^64
            #pragma unroll
            for (int p = 0; p < 4; ++p) {
                f2 npr = Pr[p] * Pr[p] - Pi[p] * Pi[p];
                f2 npi = Pr[p] * Pi[p]; npi = npi + npi;
                Pr[p] = npr; Pi[p] = npi;
            }
        }
        #pragma unroll
        for (int p = 0; p < 4; ++p) nPi[p] = f2{-Pi[p].x, -Pi[p].y};
    }

    float* spb = states + (size_t)ch * NST * 64;

    f2 Xr[4], Xi[4];
    {
        const float4 R0 = *(const float4*)(spb + m0);
        const float4 R1 = *(const float4*)(spb + m0 + 4);
        const float4 I0 = *(const float4*)(spb + 32 + m0);
        const float4 I1 = *(const float4*)(spb + 32 + m0 + 4);
        Xr[0] = f2{R0.x,R0.y}; Xr[1] = f2{R0.z,R0.w}; Xr[2] = f2{R1.x,R1.y}; Xr[3] = f2{R1.z,R1.w};
        Xi[0] = f2{I0.x,I0.y}; Xi[1] = f2{I0.z,I0.w}; Xi[2] = f2{I1.x,I1.y}; Xi[3] = f2{I1.z,I1.w};
    }

    for (int c = 1; c < NST; ++c) {
        float* sp = spb + (size_t)c * 64;
        const float4 R0 = *(const float4*)(sp + m0);
        const float4 R1 = *(const float4*)(sp + m0 + 4);
        const float4 I0 = *(const float4*)(sp + 32 + m0);
        const float4 I1 = *(const float4*)(sp + 32 + m0 + 4);
        f2 sr[4] = { f2{R0.x,R0.y}, f2{R0.z,R0.w}, f2{R1.x,R1.y}, f2{R1.z,R1.w} };
        f2 si[4] = { f2{I0.x,I0.y}, f2{I0.z,I0.w}, f2{I1.x,I1.y}, f2{I1.z,I1.w} };
        #pragma unroll
        for (int p = 0; p < 4; ++p) {
            f2 nr = pk_fma(Pr[p], Xr[p], pk_fma(nPi[p], Xi[p], sr[p]));
            f2 ni = pk_fma(Pi[p], Xr[p], pk_fma(Pr[p], Xi[p], si[p]));
            Xr[p] = nr; Xi[p] = ni;
        }
        *(float4*)(sp + m0)          = make_float4(Xr[0].x, Xr[0].y, Xr[1].x, Xr[1].y);
        *(float4*)(sp + m0 + 4)      = make_float4(Xr[2].x, Xr[2].y, Xr[3].x, Xr[3].y);
        *(float4*)(sp + 32 + m0)     = make_float4(Xi[0].x, Xi[0].y, Xi[1].x, Xi[1].y);
        *(float4*)(sp + 32 + m0 + 4) = make_float4(Xi[2].x, Xi[2].y, Xi[3].x, Xi[3].y);
    }
}

// ---- Kernel 3: outputs via MFMA  Y = T x U + M x X  ----------------------
// T: scalar lower-tri Toeplitz of kc[d]=sum_m Re(A^d B'_m) (+Dh at d=0)
// M: M[t][m]=Re(A^{t+1})_m, M[t][32+m]=-Im(A^{t+1})_m  (v-space carry)
__global__ __launch_bounds__(256) void ssm_out_mfma(
    const float* __restrict__ input, const float* __restrict__ log_dt,
    const float* __restrict__ Dp, const float* __restrict__ A_log,
    const float* __restrict__ A_imag, const float* __restrict__ Bp,
    const float* __restrict__ Cp, const float* __restrict__ states,
    float* __restrict__ out)
{
    __shared__ __align__(16) short Ms[4][64 * VP];
    __shared__ float kcs[4][CL];
    const int tid = threadIdx.x, wv = tid >> 6, l = tid & 63;
    const int g = blockIdx.x;
    const int ch = ((((g & 7) << 7) | (g >> 3)) << 2) + wv;   // XCD-grouped
    const int h = ch & (HIDDEN - 1), b = ch >> 10;
    const int ml = l & 31;
    const int lr = l & 15, lk = (l >> 4) * 8, lo = (l >> 4) * 4;

    const float* ub = input + (size_t)b * SEQLEN * HIDDEN + h;
    const float Dh = Dp[h];

    float uf[32];
    #pragma unroll
    for (int nt = 0; nt < 2; ++nt)
      #pragma unroll
      for (int ks = 0; ks < 2; ++ks) {
        const int base = (nt * 2 + ks) * 8;
        const int n  = nt * 16 + lr;
        const int k0 = ks * 32 + lk;
        #pragma unroll
        for (int j = 0; j < 8; ++j)
            uf[base + j] = ub[(size_t)(n * CL + k0 + j) * HIDDEN];
      }

    float adr, adi, bpr, bpi;
    coef1(log_dt, A_log, A_imag, Bp, Cp, h, ml, adr, adi, bpr, bpi);

    // build M (bf16, padded) and kc (f32)
    short* M  = Ms[wv];
    float* kc = kcs[wv];
    {
        float pr = adr, pi = adi;    // A^{t+1}
        float wr = bpr, wi = bpi;    // A^t B'
        for (int t = 0; t < CL; ++t) {
            if (l < 32) {
                M[t * VP + ml]      = bf16of(pr);
                M[t * VP + 32 + ml] = bf16of(-pi);
            }
            float s = sum32_to16(wr);
            if (l == 16) kc[t] = s + (t == 0 ? Dh : 0.f);
            const float npr = adr * pr - adi * pi;
            const float npi = adr * pi + adi * pr;
            pr = npr; pi = npi;
            const float nwr = adr * wr - adi * wi;
            const float nwi = adr * wi + adi * wr;
            wr = nwr; wi = nwi;
        }
    }

    // U B-frags
    Frag UB[2][2];
    #pragma unroll
    for (int nt = 0; nt < 2; ++nt)
      #pragma unroll
      for (int ks = 0; ks < 2; ++ks) {
        const int base = (nt * 2 + ks) * 8;
        #pragma unroll
        for (int q = 0; q < 4; ++q)
            UB[nt][ks].u[q] = cvt_pk_bf16(uf[base + 2 * q], uf[base + 2 * q + 1]);
      }

    f32x4 acc[4][2];
    #pragma unroll
    for (int mt = 0; mt < 4; ++mt)
      #pragma unroll
      for (int nt = 0; nt < 2; ++nt) { f32x4 z = {0.f, 0.f, 0.f, 0.f}; acc[mt][nt] = z; }

    // T x U
    #pragma unroll
    for (int ks = 0; ks < 2; ++ks) {
        Frag TA[4];
        #pragma unroll
        for (int mt = 0; mt < 4; ++mt) {
            const int t  = 16 * mt + lr;
            const int s0 = ks * 32 + lk;
            float f[8];
            #pragma unroll
            for (int j = 0; j < 8; ++j) {
                const int d = t - s0 - j;
                f[j] = (d >= 0) ? kc[d] : 0.f;
            }
            #pragma unroll
            for (int q = 0; q < 4; ++q)
                TA[mt].u[q] = cvt_pk_bf16(f[2 * q], f[2 * q + 1]);
        }
        #pragma unroll
        for (int mt = 0; mt < 4; ++mt)
          #pragma unroll
          for (int nt = 0; nt < 2; ++nt)
            acc[mt][nt] = __builtin_amdgcn_mfma_f32_16x16x32_bf16(
                TA[mt].s, UB[nt][ks].s, acc[mt][nt], 0, 0, 0);
    }

    // X B-frags (carry states; chunk 0 -> zeros)
    Frag XB[2][2];
    #pragma unroll
    for (int nt = 0; nt < 2; ++nt)
      #pragma unroll
      for (int ks = 0; ks < 2; ++ks) {
        const int n = nt * 16 + lr;
        float x[8];
        if (n > 0) {
            const float* xp = states + ((size_t)ch * NST + (n - 1)) * 64 + ks * 32 + lk;
            #pragma unroll
            for (int j = 0; j < 8; ++j) x[j] = xp[j];
        } else {
            #pragma unroll
            for (int j = 0; j < 8; ++j) x[j] = 0.f;
        }
        #pragma unroll
        for (int q = 0; q < 4; ++q)
            XB[nt][ks].u[q] = cvt_pk_bf16(x[2 * q], x[2 * q + 1]);
      }

    // M x X
    #pragma unroll
    for (int ks = 0; ks < 2; ++ks) {
        Frag MA[4];
        #pragma unroll
        for (int mt = 0; mt < 4; ++mt)
            MA[mt].s = *(const s8v*)(M + (16 * mt + lr) * VP + ks * 32 + lk);
        #pragma unroll
        for (int mt = 0; mt < 4; ++mt)
          #pragma unroll
          for (int nt = 0; nt < 2; ++nt)
            acc[mt][nt] = __builtin_amdgcn_mfma_f32_16x16x32_bf16(
                MA[mt].s, XB[nt][ks].s, acc[mt][nt], 0, 0, 0);
    }

    // store Y
    float* ob = out + (size_t)b * SEQLEN * HIDDEN + h;
    #pragma unroll
    for (int mt = 0; mt < 4; ++mt)
      #pragma unroll
      for (int nt = 0; nt < 2; ++nt) {
        const int n = nt * 16 + lr;
        #pragma unroll
        for (int r = 0; r < 4; ++r) {
            const int t = 16 * mt + lo + r;
            ob[(size_t)(n * CL + t) * HIDDEN] = acc[mt][nt][r];
        }
      }
}

extern "C" void kernel_launch(void* const* d_in, const int* in_sizes, int n_in,
                              void* d_out, int out_size, void* d_ws, size_t ws_size,
                              hipStream_t stream) {
    const float* input  = (const float*)d_in[0];
    const float* log_dt = (const float*)d_in[1];
    const float* Dp     = (const float*)d_in[2];
    const float* A_log  = (const float*)d_in[3];
    const float* A_imag = (const float*)d_in[4];
    const float* Bp     = (const float*)d_in[5];
    const float* Cp     = (const float*)d_in[6];
    float* out    = (float*)d_out;
    float* states = (float*)d_ws;    // 4096 * 31 * 64 * 4 B = 32.5 MB (proven fit)

    ssm_states_mfma<<<dim3(CHANNELS / 4), dim3(256), 0, stream>>>(
        input, log_dt, A_log, A_imag, Bp, Cp, states);
    ssm_combine<<<dim3(CHANNELS * 4 / 256), dim3(256), 0, stream>>>(
        log_dt, A_log, A_imag, states);
    ssm_out_mfma<<<dim3(CHANNELS / 4), dim3(256), 0, stream>>>(
        input, log_dt, Dp, A_log, A_imag, Bp, Cp, states, out);
}

// Round 13
// 144.826 us; speedup vs baseline: 1.0491x; 1.0491x over previous
//
#include <hip/hip_runtime.h>
#include <math.h>

#define SEQLEN   2048
#define HIDDEN   1024
#define NMODES   32
#define CHANNELS 4096
#define NST      31      // carry slots (chunks 0..30)
#define CHB      16      // channels per block (states/out)
#define TPG      512     // timesteps per chunk-group (8 chunks x 64)
#define NGC      4       // chunk groups

typedef float  f2    __attribute__((ext_vector_type(2)));
typedef short  s8v   __attribute__((ext_vector_type(8)));
typedef float  f32x4 __attribute__((ext_vector_type(4)));
union Frag { s8v s; unsigned u[4]; };

// ---- ws layout (bytes); total 33,292,288 <= proven 34,078,720 ------------
#define SZ_V  (1024*64*64*2)          // V table bf16, 8 MiB
#define SZ_M  (1024*64*64*2)          // M table bf16, 8 MiB
#define SZ_K  (1024*64*4)             // kc  f32, 256 KiB
#define OFF_M (SZ_V)
#define OFF_K (SZ_V + SZ_M)
#define OFF_S (SZ_V + SZ_M + SZ_K)    // states bf16 [ch][31][64]

// ---- helpers -------------------------------------------------------------
__device__ __forceinline__ f2 pk_fma(f2 a, f2 b, f2 c) {
    f2 d; asm("v_pk_fma_f32 %0, %1, %2, %3" : "=v"(d) : "v"(a), "v"(b), "v"(c)); return d;
}
template <int CTRL>
__device__ __forceinline__ float dpp_add(float p) {
    int t = __builtin_amdgcn_update_dpp(0, __float_as_int(p), CTRL, 0xF, 0xF, true);
    return p + __int_as_float(t);
}
// sums lanes 0-31 into lanes 16-31 and lanes 32-63 into 48-63 (proven R12)
__device__ __forceinline__ float sum32_to16(float p) {
    p = dpp_add<0xB1>(p); p = dpp_add<0x4E>(p);
    p = dpp_add<0x124>(p); p = dpp_add<0x128>(p);
    p = dpp_add<0x142>(p);
    return p;
}
__device__ __forceinline__ unsigned cvt_pk_bf16(float lo, float hi) {
    unsigned d; asm("v_cvt_pk_bf16_f32 %0, %1, %2" : "=v"(d) : "v"(lo), "v"(hi)); return d;
}
__device__ __forceinline__ unsigned short bf16of(float x) {
    return (unsigned short)(cvt_pk_bf16(x, x) & 0xffffu);
}
__device__ __forceinline__ float bf2f(unsigned short s) {
    return __uint_as_float(((unsigned)s) << 16);
}

// one mode: A_disc (bilinear alpha=0.5) and B' = Cc .* B_disc (C folded)
__device__ __forceinline__ void coef1(
    const float* __restrict__ log_dt, const float* __restrict__ A_log,
    const float* __restrict__ A_imag, const float* __restrict__ Bp,
    const float* __restrict__ Cp, int h, int m,
    float& adr, float& adi, float& bpr, float& bpi)
{
    const int idx = h * NMODES + m;
    const float dt = expf(log_dt[h]);
    const float hd = 0.5f * dt;
    const float ar = -expf(A_log[idx]);
    const float ai = A_imag[idx];
    const float dr = 1.f - hd * ar, di = -hd * ai;
    const float inv = 1.f / (dr * dr + di * di);
    const float nr = 1.f + hd * ar, ni = hd * ai;
    adr = (nr * dr + ni * di) * inv;
    adi = (ni * dr - nr * di) * inv;
    const float tbr = dt * Bp[idx * 2], tbi = dt * Bp[idx * 2 + 1];
    const float bdr = (tbr * dr + tbi * di) * inv;
    const float bdi = (tbi * dr - tbr * di) * inv;
    const float cr = 2.f * Cp[idx * 2], ci = 2.f * Cp[idx * 2 + 1];
    bpr = cr * bdr - ci * bdi;
    bpi = cr * bdi + ci * bdr;
}

// ---- Kernel 0: per-h tables, fully parallel over (h, mode, d) ------------
// V[h][m][63-d]=Re(A^d B'), V[h][32+m][63-d]=Im; M[h][d][m]=Re(A^{d+1}),
// M[h][d][32+m]=-Im; kc[h][d]=sum_m Re(A^d B') (+D at d=0).
__global__ __launch_bounds__(256) void ssm_tables(
    const float* __restrict__ log_dt, const float* __restrict__ Dp,
    const float* __restrict__ A_log, const float* __restrict__ A_imag,
    const float* __restrict__ Bp, const float* __restrict__ Cp,
    unsigned short* __restrict__ Vt, unsigned short* __restrict__ Mt,
    float* __restrict__ kct)
{
    const int h = blockIdx.x >> 3, dg = blockIdx.x & 7;
    const int tid = threadIdx.x, wv = tid >> 6, l = tid & 63;
    const int m = l & 31;
    const int d = (dg * 4 + wv) * 2 + (l >> 5);

    float adr, adi, bpr, bpi;
    coef1(log_dt, A_log, A_imag, Bp, Cp, h, m, adr, adi, bpr, bpi);

    // A^d via binary exponentiation (6 bits)
    float Pr = 1.f, Pi = 0.f, Qr = adr, Qi = adi;
    #pragma unroll
    for (int bit = 0; bit < 6; ++bit) {
        if ((d >> bit) & 1) { float t = Pr*Qr - Pi*Qi; Pi = Pr*Qi + Pi*Qr; Pr = t; }
        float tq = Qr*Qr - Qi*Qi; Qi = 2.f*Qr*Qi; Qr = tq;
    }
    const float wr  = Pr*bpr - Pi*bpi, wi  = Pr*bpi + Pi*bpr;   // A^d B'
    const float apr = Pr*adr - Pi*adi, api = Pr*adi + Pi*adr;   // A^{d+1}

    const size_t hb = (size_t)h * 64;
    Vt[(hb + m)      * 64 + (63 - d)] = bf16of(wr);
    Vt[(hb + 32 + m) * 64 + (63 - d)] = bf16of(wi);
    Mt[(hb + d) * 64 + m]       = bf16of(apr);
    Mt[(hb + d) * 64 + 32 + m]  = bf16of(-api);

    float s = sum32_to16(wr);
    if ((l & 31) == 16) kct[hb + d] = s + (d == 0 ? Dp[h] : 0.f);
}

// ---- shared staging: u tile -> frag-ordered bf16 LDS ---------------------
// ubuf element for (chl, ks, lane, j) at chl*1024 + (ks*64+lane)*8 + j holds
// u[t_loc = (lane&15)*64 + ks*32 + ((lane>>4)&3)*8 + j] for that channel.
__device__ __forceinline__ void stage_frag_u(
    const float* __restrict__ ug, unsigned short* __restrict__ ubuf, int tid)
{
    #pragma unroll
    for (int it = 0; it < 8; ++it) {
        const int t_l = it * 64 + (tid >> 2);
        const int c4  = (tid & 3) * 4;
        const float4 g = *(const float4*)(ug + (size_t)t_l * HIDDEN + c4);
        const int n = t_l >> 6, rr = t_l & 63, ksw = rr >> 5, r5 = rr & 31;
        const int lane = (r5 >> 3) * 16 + n, j = r5 & 7;
        const int base = (ksw * 64 + lane) * 8 + j;
        ubuf[(c4 + 0) * 1024 + base] = bf16of(g.x);
        ubuf[(c4 + 1) * 1024 + base] = bf16of(g.y);
        ubuf[(c4 + 2) * 1024 + base] = bf16of(g.z);
        ubuf[(c4 + 3) * 1024 + base] = bf16of(g.w);
    }
    __syncthreads();
}

// ---- Kernel 1: local chunk end states, Xend = V x U (MFMA) ---------------
// Block = 256 thr = 16 channels x 8 chunks. Wave handles 4 channels.
__global__ __launch_bounds__(256) void ssm_states(
    const float* __restrict__ input, const unsigned short* __restrict__ Vt,
    unsigned short* __restrict__ stb)
{
    __shared__ __align__(16) unsigned short ubuf[CHB * 1024];
    const int tid = threadIdx.x, wv = tid >> 6, l = tid & 63;
    const int chb = blockIdx.x >> 2, cg = blockIdx.x & 3;
    const int chbase = chb * CHB;
    const int b = chbase >> 10, h0 = chbase & (HIDDEN - 1);
    const int lr = l & 15, lk8 = ((l >> 4) & 3) * 8, lo = (l >> 4) * 4;

    stage_frag_u(input + ((size_t)b * SEQLEN + cg * TPG) * HIDDEN + h0, ubuf, tid);

    #pragma unroll 1
    for (int c = 0; c < 4; ++c) {
        const int chl = wv * 4 + c, ch = chbase + chl, h = h0 + chl;
        Frag UB[2];
        UB[0].s = *(const s8v*)(ubuf + chl * 1024 + l * 8);
        UB[1].s = *(const s8v*)(ubuf + chl * 1024 + (64 + l) * 8);

        f32x4 acc[4];
        #pragma unroll
        for (int mt = 0; mt < 4; ++mt) { f32x4 z = {0.f,0.f,0.f,0.f}; acc[mt] = z; }

        const unsigned short* Vh = Vt + (size_t)h * 64 * 64;
        #pragma unroll
        for (int ks = 0; ks < 2; ++ks) {
            #pragma unroll
            for (int mt = 0; mt < 4; ++mt) {
                Frag VA; VA.s = *(const s8v*)(Vh + (16 * mt + lr) * 64 + ks * 32 + lk8);
                acc[mt] = __builtin_amdgcn_mfma_f32_16x16x32_bf16(
                    VA.s, UB[ks].s, acc[mt], 0, 0, 0);
            }
        }

        const int gslot = cg * 8 + lr;
        if (lr < 8 && gslot < NST) {
            unsigned short* sp = stb + ((size_t)ch * NST + gslot) * 64;
            #pragma unroll
            for (int mt = 0; mt < 4; ++mt)
                #pragma unroll
                for (int r = 0; r < 4; ++r)
                    sp[16 * mt + lo + r] = bf16of(acc[mt][r]);
        }
    }
}

// ---- Kernel 2 (tiny): in-place serial prefix over bf16 chunk states ------
__global__ void ssm_combine(
    const float* __restrict__ log_dt, const float* __restrict__ A_log,
    const float* __restrict__ A_imag, unsigned short* __restrict__ stb)
{
    const int gid = blockIdx.x * 256 + threadIdx.x;
    const int ch = gid >> 2, ll = gid & 3;
    const int h = ch & (HIDDEN - 1), m0 = ll * 8;

    // Apow = A^64 for 8 modes
    f2 Pr[4], Pi[4], nPi[4];
    {
        float adr[8], adi[8];
        const float dt = expf(log_dt[h]);
        #pragma unroll
        for (int k = 0; k < 8; ++k) {
            const int idx = h * NMODES + m0 + k;
            const float hd = 0.5f * dt;
            const float ar = -expf(A_log[idx]), ai = A_imag[idx];
            const float dr = 1.f - hd * ar, di = -hd * ai;
            const float inv = 1.f / (dr * dr + di * di);
            const float nr = 1.f + hd * ar, ni = hd * ai;
            adr[k] = (nr * dr + ni * di) * inv;
            adi[k] = (ni * dr - nr * di) * inv;
        }
        #pragma unroll
        for (int p = 0; p < 4; ++p) { Pr[p] = f2{adr[2*p], adr[2*p+1]}; Pi[p] = f2{adi[2*p], adi[2*p+1]}; }
        #pragma unroll
        for (int s = 0; s < 6; ++s)
            #pragma unroll
            for (int p = 0; p < 4; ++p) {
                f2 npr = Pr[p]*Pr[p] - Pi[p]*Pi[p];
                f2 npi = Pr[p]*Pi[p]; npi = npi + npi;
                Pr[p] = npr; Pi[p] = npi;
            }
        #pragma unroll
        for (int p = 0; p < 4; ++p) nPi[p] = f2{-Pi[p].x, -Pi[p].y};
    }

    unsigned short* spb = stb + (size_t)ch * NST * 64;

    f2 Xr[4], Xi[4];
    {
        s8v vr_ = *(const s8v*)(spb + m0);
        s8v vi_ = *(const s8v*)(spb + 32 + m0);
        #pragma unroll
        for (int k = 0; k < 4; ++k) {
            Xr[k] = f2{bf2f((unsigned short)vr_[2*k]), bf2f((unsigned short)vr_[2*k+1])};
            Xi[k] = f2{bf2f((unsigned short)vi_[2*k]), bf2f((unsigned short)vi_[2*k+1])};
        }
    }

    for (int c = 1; c < NST; ++c) {
        unsigned short* sp = spb + (size_t)c * 64;
        s8v vr_ = *(const s8v*)(sp + m0);
        s8v vi_ = *(const s8v*)(sp + 32 + m0);
        #pragma unroll
        for (int p = 0; p < 4; ++p) {
            f2 sr = f2{bf2f((unsigned short)vr_[2*p]), bf2f((unsigned short)vr_[2*p+1])};
            f2 si = f2{bf2f((unsigned short)vi_[2*p]), bf2f((unsigned short)vi_[2*p+1])};
            f2 nr = pk_fma(Pr[p], Xr[p], pk_fma(nPi[p], Xi[p], sr));
            f2 ni = pk_fma(Pi[p], Xr[p], pk_fma(Pr[p], Xi[p], si));
            Xr[p] = nr; Xi[p] = ni;
        }
        uint4 wr, wi;
        wr.x = cvt_pk_bf16(Xr[0].x, Xr[0].y); wr.y = cvt_pk_bf16(Xr[1].x, Xr[1].y);
        wr.z = cvt_pk_bf16(Xr[2].x, Xr[2].y); wr.w = cvt_pk_bf16(Xr[3].x, Xr[3].y);
        wi.x = cvt_pk_bf16(Xi[0].x, Xi[0].y); wi.y = cvt_pk_bf16(Xi[1].x, Xi[1].y);
        wi.z = cvt_pk_bf16(Xi[2].x, Xi[2].y); wi.w = cvt_pk_bf16(Xi[3].x, Xi[3].y);
        *(uint4*)(sp + m0)      = wr;
        *(uint4*)(sp + 32 + m0) = wi;
    }
}

// ---- Kernel 3: Y = T x U + M x X (MFMA) ----------------------------------
__global__ __launch_bounds__(256) void ssm_out(
    const float* __restrict__ input, const unsigned short* __restrict__ Mt,
    const float* __restrict__ kct, const unsigned short* __restrict__ stb,
    float* __restrict__ out)
{
    __shared__ __align__(16) unsigned short ubuf[CHB * 1024];
    __shared__ float kcP[CHB][128];   // reversed kc, zero-padded (d<0 -> 0)
    const int tid = threadIdx.x, wv = tid >> 6, l = tid & 63;
    const int chb = blockIdx.x >> 2, cg = blockIdx.x & 3;
    const int chbase = chb * CHB;
    const int b = chbase >> 10, h0 = chbase & (HIDDEN - 1);
    const int lr = l & 15, lk8 = ((l >> 4) & 3) * 8, lo = (l >> 4) * 4;

    // stage kcP (P[k] = kc[63-k] for k<64 else 0)
    #pragma unroll
    for (int q = 0; q < 8; ++q) {
        const int idx = q * 256 + tid, chl = idx >> 7, k = idx & 127;
        kcP[chl][k] = (k < 64) ? kct[(size_t)(h0 + chl) * 64 + (63 - k)] : 0.f;
    }
    stage_frag_u(input + ((size_t)b * SEQLEN + cg * TPG) * HIDDEN + h0, ubuf, tid);

    #pragma unroll 1
    for (int c = 0; c < 4; ++c) {
        const int chl = wv * 4 + c, ch = chbase + chl, h = h0 + chl;
        Frag UB[2];
        UB[0].s = *(const s8v*)(ubuf + chl * 1024 + l * 8);
        UB[1].s = *(const s8v*)(ubuf + chl * 1024 + (64 + l) * 8);

        f32x4 acc[4];
        #pragma unroll
        for (int mt = 0; mt < 4; ++mt) { f32x4 z = {0.f,0.f,0.f,0.f}; acc[mt] = z; }

        // T x U : T-frags gathered from kcP
        #pragma unroll
        for (int ks = 0; ks < 2; ++ks) {
            #pragma unroll
            for (int mt = 0; mt < 4; ++mt) {
                const int base = 63 - 16 * mt + 32 * ks + lk8 - lr;
                float f[8];
                #pragma unroll
                for (int j = 0; j < 8; ++j) f[j] = kcP[chl][base + j];
                Frag TA;
                #pragma unroll
                for (int q = 0; q < 4; ++q) TA.u[q] = cvt_pk_bf16(f[2*q], f[2*q+1]);
                acc[mt] = __builtin_amdgcn_mfma_f32_16x16x32_bf16(
                    TA.s, UB[ks].s, acc[mt], 0, 0, 0);
            }
        }

        // M x X : carry term
        const int gc = cg * 8 + lr;
        const bool xv = (lr < 8) && (gc > 0);
        Frag XB[2];
        #pragma unroll
        for (int ks = 0; ks < 2; ++ks) {
            if (xv) XB[ks].s = *(const s8v*)(stb + ((size_t)ch * NST + gc - 1) * 64 + ks * 32 + lk8);
            else { XB[ks].u[0] = XB[ks].u[1] = XB[ks].u[2] = XB[ks].u[3] = 0; }
        }
        const unsigned short* Mh = Mt + (size_t)h * 64 * 64;
        #pragma unroll
        for (int ks = 0; ks < 2; ++ks) {
            #pragma unroll
            for (int mt = 0; mt < 4; ++mt) {
                Frag MA; MA.s = *(const s8v*)(Mh + (16 * mt + lr) * 64 + ks * 32 + lk8);
                acc[mt] = __builtin_amdgcn_mfma_f32_16x16x32_bf16(
                    MA.s, XB[ks].s, acc[mt], 0, 0, 0);
            }
        }

        // store Y (cols lr>=8 are padding)
        float* ob = out + (size_t)b * SEQLEN * HIDDEN + h;
        if (lr < 8) {
            #pragma unroll
            for (int mt = 0; mt < 4; ++mt)
                #pragma unroll
                for (int r = 0; r < 4; ++r)
                    ob[(size_t)(gc * 64 + 16 * mt + lo + r) * HIDDEN] = acc[mt][r];
        }
    }
}

extern "C" void kernel_launch(void* const* d_in, const int* in_sizes, int n_in,
                              void* d_out, int out_size, void* d_ws, size_t ws_size,
                              hipStream_t stream) {
    const float* input  = (const float*)d_in[0];
    const float* log_dt = (const float*)d_in[1];
    const float* Dp     = (const float*)d_in[2];
    const float* A_log  = (const float*)d_in[3];
    const float* A_imag = (const float*)d_in[4];
    const float* Bp     = (const float*)d_in[5];
    const float* Cp     = (const float*)d_in[6];
    float* out = (float*)d_out;

    unsigned short* Vt  = (unsigned short*)d_ws;
    unsigned short* Mtb = (unsigned short*)((char*)d_ws + OFF_M);
    float*          kct = (float*)((char*)d_ws + OFF_K);
    unsigned short* stb = (unsigned short*)((char*)d_ws + OFF_S);

    ssm_tables<<<dim3(1024 * 8), dim3(256), 0, stream>>>(
        log_dt, Dp, A_log, A_imag, Bp, Cp, Vt, Mtb, kct);
    ssm_states<<<dim3((CHANNELS / CHB) * NGC), dim3(256), 0, stream>>>(
        input, Vt, stb);
    ssm_combine<<<dim3(CHANNELS * 4 / 256), dim3(256), 0, stream>>>(
        log_dt, A_log, A_imag, stb);
    ssm_out<<<dim3((CHANNELS / CHB) * NGC), dim3(256), 0, stream>>>(
        input, Mtb, kct, stb, out);
}

// Round 14
// 107.197 us; speedup vs baseline: 1.4173x; 1.3510x over previous
//
#include <hip/hip_runtime.h>
#include <math.h>

#define SEQLEN   2048
#define HIDDEN   1024
#define NMODES   32
#define CHANNELS 4096
#define NST      31      // carry slots (chunks 0..30)
#define CHB      16      // channels per block (states/out)
#define TPG      512     // timesteps per chunk-group (8 chunks x 64)
#define NGC      4       // chunk groups

typedef float  f2    __attribute__((ext_vector_type(2)));
typedef short  s8v   __attribute__((ext_vector_type(8)));
typedef float  f32x4 __attribute__((ext_vector_type(4)));
union Frag { s8v s; unsigned u[4]; };

// ---- ws layout (bytes); total 33,292,288 <= proven 34,078,720 ------------
#define SZ_V  (1024*64*64*2)          // V table bf16, 8 MiB
#define SZ_M  (1024*64*64*2)          // M table bf16, 8 MiB
#define SZ_K  (1024*64*4)             // kc  f32, 256 KiB
#define OFF_M (SZ_V)
#define OFF_K (SZ_V + SZ_M)
#define OFF_S (SZ_V + SZ_M + SZ_K)    // states bf16 [ch][31][64]

// ---- helpers -------------------------------------------------------------
__device__ __forceinline__ f2 pk_fma(f2 a, f2 b, f2 c) {
    f2 d; asm("v_pk_fma_f32 %0, %1, %2, %3" : "=v"(d) : "v"(a), "v"(b), "v"(c)); return d;
}
template <int CTRL>
__device__ __forceinline__ float dpp_add(float p) {
    int t = __builtin_amdgcn_update_dpp(0, __float_as_int(p), CTRL, 0xF, 0xF, true);
    return p + __int_as_float(t);
}
__device__ __forceinline__ float sum32_to16(float p) {
    p = dpp_add<0xB1>(p); p = dpp_add<0x4E>(p);
    p = dpp_add<0x124>(p); p = dpp_add<0x128>(p);
    p = dpp_add<0x142>(p);
    return p;
}
__device__ __forceinline__ unsigned cvt_pk_bf16(float lo, float hi) {
    unsigned d; asm("v_cvt_pk_bf16_f32 %0, %1, %2" : "=v"(d) : "v"(lo), "v"(hi)); return d;
}
__device__ __forceinline__ unsigned short bf16of(float x) {
    return (unsigned short)(cvt_pk_bf16(x, x) & 0xffffu);
}
__device__ __forceinline__ float bf2f(unsigned s) {
    return __uint_as_float(s << 16);
}

// one mode: A_disc (bilinear alpha=0.5) and B' = Cc .* B_disc (C folded)
__device__ __forceinline__ void coef1(
    const float* __restrict__ log_dt, const float* __restrict__ A_log,
    const float* __restrict__ A_imag, const float* __restrict__ Bp,
    const float* __restrict__ Cp, int h, int m,
    float& adr, float& adi, float& bpr, float& bpi)
{
    const int idx = h * NMODES + m;
    const float dt = expf(log_dt[h]);
    const float hd = 0.5f * dt;
    const float ar = -expf(A_log[idx]);
    const float ai = A_imag[idx];
    const float dr = 1.f - hd * ar, di = -hd * ai;
    const float inv = 1.f / (dr * dr + di * di);
    const float nr = 1.f + hd * ar, ni = hd * ai;
    adr = (nr * dr + ni * di) * inv;
    adi = (ni * dr - nr * di) * inv;
    const float tbr = dt * Bp[idx * 2], tbi = dt * Bp[idx * 2 + 1];
    const float bdr = (tbr * dr + tbi * di) * inv;
    const float bdi = (tbi * dr - tbr * di) * inv;
    const float cr = 2.f * Cp[idx * 2], ci = 2.f * Cp[idx * 2 + 1];
    bpr = cr * bdr - ci * bdi;
    bpi = cr * bdi + ci * bdr;
}

// ---- Kernel 0: per-h tables (parallel over h, mode, d) -------------------
__global__ __launch_bounds__(256) void ssm_tables(
    const float* __restrict__ log_dt, const float* __restrict__ Dp,
    const float* __restrict__ A_log, const float* __restrict__ A_imag,
    const float* __restrict__ Bp, const float* __restrict__ Cp,
    unsigned short* __restrict__ Vt, unsigned short* __restrict__ Mt,
    float* __restrict__ kct)
{
    const int h = blockIdx.x >> 3, dg = blockIdx.x & 7;
    const int tid = threadIdx.x, wv = tid >> 6, l = tid & 63;
    const int m = l & 31;
    const int d = (dg * 4 + wv) * 2 + (l >> 5);

    float adr, adi, bpr, bpi;
    coef1(log_dt, A_log, A_imag, Bp, Cp, h, m, adr, adi, bpr, bpi);

    float Pr = 1.f, Pi = 0.f, Qr = adr, Qi = adi;
    #pragma unroll
    for (int bit = 0; bit < 6; ++bit) {
        if ((d >> bit) & 1) { float t = Pr*Qr - Pi*Qi; Pi = Pr*Qi + Pi*Qr; Pr = t; }
        float tq = Qr*Qr - Qi*Qi; Qi = 2.f*Qr*Qi; Qr = tq;
    }
    const float wr  = Pr*bpr - Pi*bpi, wi  = Pr*bpi + Pi*bpr;   // A^d B'
    const float apr = Pr*adr - Pi*adi, api = Pr*adi + Pi*adr;   // A^{d+1}

    const size_t hb = (size_t)h * 64;
    Vt[(hb + m)      * 64 + (63 - d)] = bf16of(wr);
    Vt[(hb + 32 + m) * 64 + (63 - d)] = bf16of(wi);
    Mt[(hb + d) * 64 + m]       = bf16of(apr);
    Mt[(hb + d) * 64 + 32 + m]  = bf16of(-api);

    float s = sum32_to16(wr);
    if ((l & 31) == 16) kct[hb + d] = s + (d == 0 ? Dp[h] : 0.f);
}

// ---- shared staging: u tile -> frag-ordered bf16 LDS ---------------------
__device__ __forceinline__ void stage_frag_u(
    const float* __restrict__ ug, unsigned short* __restrict__ ubuf, int tid)
{
    #pragma unroll
    for (int it = 0; it < 8; ++it) {
        const int t_l = it * 64 + (tid >> 2);
        const int c4  = (tid & 3) * 4;
        const float4 g = *(const float4*)(ug + (size_t)t_l * HIDDEN + c4);
        const int n = t_l >> 6, rr = t_l & 63, ksw = rr >> 5, r5 = rr & 31;
        const int lane = (r5 >> 3) * 16 + n, j = r5 & 7;
        const int base = (ksw * 64 + lane) * 8 + j;
        ubuf[(c4 + 0) * 1024 + base] = bf16of(g.x);
        ubuf[(c4 + 1) * 1024 + base] = bf16of(g.y);
        ubuf[(c4 + 2) * 1024 + base] = bf16of(g.z);
        ubuf[(c4 + 3) * 1024 + base] = bf16of(g.w);
    }
    __syncthreads();
}

// ---- Kernel 1: local chunk end states, Xend = V x U (MFMA) ---------------
__global__ __launch_bounds__(256) void ssm_states(
    const float* __restrict__ input, const unsigned short* __restrict__ Vt,
    unsigned short* __restrict__ stb)
{
    __shared__ __align__(16) unsigned short ubuf[CHB * 1024];
    const int tid = threadIdx.x, wv = tid >> 6, l = tid & 63;
    const int chb = blockIdx.x >> 2, cg = blockIdx.x & 3;
    const int chbase = chb * CHB;
    const int b = chbase >> 10, h0 = chbase & (HIDDEN - 1);
    const int lr = l & 15, lk8 = ((l >> 4) & 3) * 8, lo = (l >> 4) * 4;

    stage_frag_u(input + ((size_t)b * SEQLEN + cg * TPG) * HIDDEN + h0, ubuf, tid);

    #pragma unroll 1
    for (int c = 0; c < 4; ++c) {
        const int chl = wv * 4 + c, ch = chbase + chl, h = h0 + chl;
        Frag UB[2];
        UB[0].s = *(const s8v*)(ubuf + chl * 1024 + l * 8);
        UB[1].s = *(const s8v*)(ubuf + chl * 1024 + (64 + l) * 8);

        f32x4 acc[4];
        #pragma unroll
        for (int mt = 0; mt < 4; ++mt) { f32x4 z = {0.f,0.f,0.f,0.f}; acc[mt] = z; }

        const unsigned short* Vh = Vt + (size_t)h * 64 * 64;
        #pragma unroll
        for (int ks = 0; ks < 2; ++ks) {
            #pragma unroll
            for (int mt = 0; mt < 4; ++mt) {
                Frag VA; VA.s = *(const s8v*)(Vh + (16 * mt + lr) * 64 + ks * 32 + lk8);
                acc[mt] = __builtin_amdgcn_mfma_f32_16x16x32_bf16(
                    VA.s, UB[ks].s, acc[mt], 0, 0, 0);
            }
        }

        const int gslot = cg * 8 + lr;
        if (lr < 8 && gslot < NST) {
            unsigned short* sp = stb + ((size_t)ch * NST + gslot) * 64;
            #pragma unroll
            for (int mt = 0; mt < 4; ++mt) {
                uint2 w;
                w.x = cvt_pk_bf16(acc[mt][0], acc[mt][1]);
                w.y = cvt_pk_bf16(acc[mt][2], acc[mt][3]);
                *(uint2*)(sp + 16 * mt + lo) = w;   // 8B packed store
            }
        }
    }
}

// ---- Kernel 2 (tiny): in-place serial prefix over bf16 chunk states ------
__global__ void ssm_combine(
    const float* __restrict__ log_dt, const float* __restrict__ A_log,
    const float* __restrict__ A_imag, unsigned short* __restrict__ stb)
{
    const int gid = blockIdx.x * 256 + threadIdx.x;
    const int ch = gid >> 2, ll = gid & 3;
    const int h = ch & (HIDDEN - 1), m0 = ll * 8;

    f2 Pr[4], Pi[4], nPi[4];
    {
        float adr[8], adi[8];
        const float dt = expf(log_dt[h]);
        #pragma unroll
        for (int k = 0; k < 8; ++k) {
            const int idx = h * NMODES + m0 + k;
            const float hd = 0.5f * dt;
            const float ar = -expf(A_log[idx]), ai = A_imag[idx];
            const float dr = 1.f - hd * ar, di = -hd * ai;
            const float inv = 1.f / (dr * dr + di * di);
            const float nr = 1.f + hd * ar, ni = hd * ai;
            adr[k] = (nr * dr + ni * di) * inv;
            adi[k] = (ni * dr - nr * di) * inv;
        }
        #pragma unroll
        for (int p = 0; p < 4; ++p) { Pr[p] = f2{adr[2*p], adr[2*p+1]}; Pi[p] = f2{adi[2*p], adi[2*p+1]}; }
        #pragma unroll
        for (int s = 0; s < 6; ++s)
            #pragma unroll
            for (int p = 0; p < 4; ++p) {
                f2 npr = Pr[p]*Pr[p] - Pi[p]*Pi[p];
                f2 npi = Pr[p]*Pi[p]; npi = npi + npi;
                Pr[p] = npr; Pi[p] = npi;
            }
        #pragma unroll
        for (int p = 0; p < 4; ++p) nPi[p] = f2{-Pi[p].x, -Pi[p].y};
    }

    unsigned short* spb = stb + (size_t)ch * NST * 64;

    f2 Xr[4], Xi[4];
    {
        s8v vr_ = *(const s8v*)(spb + m0);
        s8v vi_ = *(const s8v*)(spb + 32 + m0);
        #pragma unroll
        for (int k = 0; k < 4; ++k) {
            Xr[k] = f2{bf2f((unsigned short)vr_[2*k]), bf2f((unsigned short)vr_[2*k+1])};
            Xi[k] = f2{bf2f((unsigned short)vi_[2*k]), bf2f((unsigned short)vi_[2*k+1])};
        }
    }

    for (int c = 1; c < NST; ++c) {
        unsigned short* sp = spb + (size_t)c * 64;
        s8v vr_ = *(const s8v*)(sp + m0);
        s8v vi_ = *(const s8v*)(sp + 32 + m0);
        #pragma unroll
        for (int p = 0; p < 4; ++p) {
            f2 sr = f2{bf2f((unsigned short)vr_[2*p]), bf2f((unsigned short)vr_[2*p+1])};
            f2 si = f2{bf2f((unsigned short)vi_[2*p]), bf2f((unsigned short)vi_[2*p+1])};
            f2 nr = pk_fma(Pr[p], Xr[p], pk_fma(nPi[p], Xi[p], sr));
            f2 ni = pk_fma(Pi[p], Xr[p], pk_fma(Pr[p], Xi[p], si));
            Xr[p] = nr; Xi[p] = ni;
        }
        uint4 wr, wi;
        wr.x = cvt_pk_bf16(Xr[0].x, Xr[0].y); wr.y = cvt_pk_bf16(Xr[1].x, Xr[1].y);
        wr.z = cvt_pk_bf16(Xr[2].x, Xr[2].y); wr.w = cvt_pk_bf16(Xr[3].x, Xr[3].y);
        wi.x = cvt_pk_bf16(Xi[0].x, Xi[0].y); wi.y = cvt_pk_bf16(Xi[1].x, Xi[1].y);
        wi.z = cvt_pk_bf16(Xi[2].x, Xi[2].y); wi.w = cvt_pk_bf16(Xi[3].x, Xi[3].y);
        *(uint4*)(sp + m0)      = wr;
        *(uint4*)(sp + 32 + m0) = wi;
    }
}

// ---- Kernel 3: Y = T x U + M x X (MFMA), LDS-repacked coalesced store ----
__global__ __launch_bounds__(256) void ssm_out(
    const float* __restrict__ input, const unsigned short* __restrict__ Mt,
    const float* __restrict__ kct, const unsigned short* __restrict__ stb,
    float* __restrict__ out)
{
    __shared__ __align__(16) unsigned short ubuf[CHB * 1024];  // u frags, then y tile
    __shared__ float kcP[CHB][128];   // reversed kc, zero-padded (d<0 -> 0)
    const int tid = threadIdx.x, wv = tid >> 6, l = tid & 63;
    const int chb = blockIdx.x >> 2, cg = blockIdx.x & 3;
    const int chbase = chb * CHB;
    const int b = chbase >> 10, h0 = chbase & (HIDDEN - 1);
    const int lr = l & 15, lk8 = ((l >> 4) & 3) * 8, lo = (l >> 4) * 4;

    #pragma unroll
    for (int q = 0; q < 8; ++q) {
        const int idx = q * 256 + tid, chl = idx >> 7, k = idx & 127;
        kcP[chl][k] = (k < 64) ? kct[(size_t)(h0 + chl) * 64 + (63 - k)] : 0.f;
    }
    stage_frag_u(input + ((size_t)b * SEQLEN + cg * TPG) * HIDDEN + h0, ubuf, tid);

    // hold all 16 accumulators across the c-loop (ubuf stays u until barrier)
    f32x4 acc[4][4];
    #pragma unroll
    for (int c = 0; c < 4; ++c) {
        const int chl = wv * 4 + c, ch = chbase + chl, h = h0 + chl;
        Frag UB[2];
        UB[0].s = *(const s8v*)(ubuf + chl * 1024 + l * 8);
        UB[1].s = *(const s8v*)(ubuf + chl * 1024 + (64 + l) * 8);

        #pragma unroll
        for (int mt = 0; mt < 4; ++mt) { f32x4 z = {0.f,0.f,0.f,0.f}; acc[c][mt] = z; }

        // T x U
        #pragma unroll
        for (int ks = 0; ks < 2; ++ks) {
            #pragma unroll
            for (int mt = 0; mt < 4; ++mt) {
                const int base = 63 - 16 * mt + 32 * ks + lk8 - lr;
                float f[8];
                #pragma unroll
                for (int j = 0; j < 8; ++j) f[j] = kcP[chl][base + j];
                Frag TA;
                #pragma unroll
                for (int q = 0; q < 4; ++q) TA.u[q] = cvt_pk_bf16(f[2*q], f[2*q+1]);
                acc[c][mt] = __builtin_amdgcn_mfma_f32_16x16x32_bf16(
                    TA.s, UB[ks].s, acc[c][mt], 0, 0, 0);
            }
        }

        // M x X
        const int gc = cg * 8 + lr;
        const bool xv = (lr < 8) && (gc > 0);
        Frag XB[2];
        #pragma unroll
        for (int ks = 0; ks < 2; ++ks) {
            if (xv) XB[ks].s = *(const s8v*)(stb + ((size_t)ch * NST + gc - 1) * 64 + ks * 32 + lk8);
            else { XB[ks].u[0] = XB[ks].u[1] = XB[ks].u[2] = XB[ks].u[3] = 0; }
        }
        const unsigned short* Mh = Mt + (size_t)h * 64 * 64;
        #pragma unroll
        for (int ks = 0; ks < 2; ++ks) {
            #pragma unroll
            for (int mt = 0; mt < 4; ++mt) {
                Frag MA; MA.s = *(const s8v*)(Mh + (16 * mt + lr) * 64 + ks * 32 + lk8);
                acc[c][mt] = __builtin_amdgcn_mfma_f32_16x16x32_bf16(
                    MA.s, XB[ks].s, acc[c][mt], 0, 0, 0);
            }
        }
    }

    __syncthreads();   // all ubuf reads done -> reuse as y tile [512][32] bf16

    // write y, XOR-swizzled col = chl ^ (lr<<1) (<=4-way banks)
    if (lr < 8) {
        #pragma unroll
        for (int c = 0; c < 4; ++c) {
            const int chl = wv * 4 + c;
            const int col = chl ^ (lr << 1);
            #pragma unroll
            for (int mt = 0; mt < 4; ++mt)
                #pragma unroll
                for (int r = 0; r < 4; ++r) {
                    const int t_loc = lr * 64 + 16 * mt + lo + r;
                    ubuf[t_loc * 32 + col] = bf16of(acc[c][mt][r]);
                }
        }
    }
    __syncthreads();

    // coalesced flush: each wave instruction writes 16 full 64B lines
    float* ob = out + ((size_t)b * SEQLEN + cg * TPG) * HIDDEN + h0;
    #pragma unroll
    for (int q = 0; q < 8; ++q) {
        const int idx = q * 256 + tid;
        const int t_loc = idx >> 2, a = idx & 3;
        const int lrt = (t_loc >> 6) & 7;
        const int blk = (a ^ (lrt >> 1)) * 4;
        const uint2 w = *(const uint2*)(ubuf + t_loc * 32 + blk);
        const float s0 = bf2f(w.x & 0xffffu), s1 = bf2f(w.x >> 16);
        const float s2 = bf2f(w.y & 0xffffu), s3 = bf2f(w.y >> 16);
        float4 o;
        if (lrt & 1) o = make_float4(s2, s3, s0, s1);
        else         o = make_float4(s0, s1, s2, s3);
        *(float4*)(ob + (size_t)t_loc * HIDDEN + blk * 0 + a * 4) = o;
    }
}

extern "C" void kernel_launch(void* const* d_in, const int* in_sizes, int n_in,
                              void* d_out, int out_size, void* d_ws, size_t ws_size,
                              hipStream_t stream) {
    const float* input  = (const float*)d_in[0];
    const float* log_dt = (const float*)d_in[1];
    const float* Dp     = (const float*)d_in[2];
    const float* A_log  = (const float*)d_in[3];
    const float* A_imag = (const float*)d_in[4];
    const float* Bp     = (const float*)d_in[5];
    const float* Cp     = (const float*)d_in[6];
    float* out = (float*)d_out;

    unsigned short* Vt  = (unsigned short*)d_ws;
    unsigned short* Mtb = (unsigned short*)((char*)d_ws + OFF_M);
    float*          kct = (float*)((char*)d_ws + OFF_K);
    unsigned short* stb = (unsigned short*)((char*)d_ws + OFF_S);

    ssm_tables<<<dim3(1024 * 8), dim3(256), 0, stream>>>(
        log_dt, Dp, A_log, A_imag, Bp, Cp, Vt, Mtb, kct);
    ssm_states<<<dim3((CHANNELS / CHB) * NGC), dim3(256), 0, stream>>>(
        input, Vt, stb);
    ssm_combine<<<dim3(CHANNELS * 4 / 256), dim3(256), 0, stream>>>(
        log_dt, A_log, A_imag, stb);
    ssm_out<<<dim3((CHANNELS / CHB) * NGC), dim3(256), 0, stream>>>(
        input, Mtb, kct, stb, out);
}

// Round 15
// 85.876 us; speedup vs baseline: 1.7692x; 1.2483x over previous
//
#include <hip/hip_runtime.h>
#include <math.h>

#define SEQLEN   2048
#define HIDDEN   1024
#define NMODES   32
#define CHANNELS 4096
#define NST      31      // carry slots (chunks 0..30)
#define CHB      16      // channels per block (states/out)
#define TPG      1024    // timesteps per chunk-group (16 chunks x 64)
#define NGC      2       // chunk groups

typedef float  f2    __attribute__((ext_vector_type(2)));
typedef short  s8v   __attribute__((ext_vector_type(8)));
typedef float  f32x4 __attribute__((ext_vector_type(4)));
union Frag { s8v s; unsigned u[4]; };

// ---- ws layout (bytes); total 33,292,288 <= proven 34,078,720 ------------
#define SZ_V  (1024*64*64*2)          // V table bf16, 8 MiB
#define SZ_M  (1024*64*64*2)          // M table bf16, 8 MiB
#define SZ_K  (1024*64*4)             // kc  f32, 256 KiB
#define OFF_M (SZ_V)
#define OFF_K (SZ_V + SZ_M)
#define OFF_S (SZ_V + SZ_M + SZ_K)    // states bf16 [ch][31][64]

// ---- helpers -------------------------------------------------------------
__device__ __forceinline__ f2 pk_fma(f2 a, f2 b, f2 c) {
    f2 d; asm("v_pk_fma_f32 %0, %1, %2, %3" : "=v"(d) : "v"(a), "v"(b), "v"(c)); return d;
}
template <int CTRL>
__device__ __forceinline__ float dpp_add(float p) {
    int t = __builtin_amdgcn_update_dpp(0, __float_as_int(p), CTRL, 0xF, 0xF, true);
    return p + __int_as_float(t);
}
__device__ __forceinline__ float sum32_to16(float p) {
    p = dpp_add<0xB1>(p); p = dpp_add<0x4E>(p);
    p = dpp_add<0x124>(p); p = dpp_add<0x128>(p);
    p = dpp_add<0x142>(p);
    return p;
}
__device__ __forceinline__ unsigned cvt_pk_bf16(float lo, float hi) {
    unsigned d; asm("v_cvt_pk_bf16_f32 %0, %1, %2" : "=v"(d) : "v"(lo), "v"(hi)); return d;
}
__device__ __forceinline__ unsigned short bf16of(float x) {
    return (unsigned short)(cvt_pk_bf16(x, x) & 0xffffu);
}
__device__ __forceinline__ float bf2f(unsigned s) {
    return __uint_as_float(s << 16);
}

// one mode: A_disc (bilinear alpha=0.5) and B' = Cc .* B_disc (C folded)
__device__ __forceinline__ void coef1(
    const float* __restrict__ log_dt, const float* __restrict__ A_log,
    const float* __restrict__ A_imag, const float* __restrict__ Bp,
    const float* __restrict__ Cp, int h, int m,
    float& adr, float& adi, float& bpr, float& bpi)
{
    const int idx = h * NMODES + m;
    const float dt = expf(log_dt[h]);
    const float hd = 0.5f * dt;
    const float ar = -expf(A_log[idx]);
    const float ai = A_imag[idx];
    const float dr = 1.f - hd * ar, di = -hd * ai;
    const float inv = 1.f / (dr * dr + di * di);
    const float nr = 1.f + hd * ar, ni = hd * ai;
    adr = (nr * dr + ni * di) * inv;
    adi = (ni * dr - nr * di) * inv;
    const float tbr = dt * Bp[idx * 2], tbi = dt * Bp[idx * 2 + 1];
    const float bdr = (tbr * dr + tbi * di) * inv;
    const float bdi = (tbi * dr - tbr * di) * inv;
    const float cr = 2.f * Cp[idx * 2], ci = 2.f * Cp[idx * 2 + 1];
    bpr = cr * bdr - ci * bdi;
    bpi = cr * bdi + ci * bdr;
}

// ---- Kernel 0: per-h tables (parallel over h, mode, d) -------------------
__global__ __launch_bounds__(256) void ssm_tables(
    const float* __restrict__ log_dt, const float* __restrict__ Dp,
    const float* __restrict__ A_log, const float* __restrict__ A_imag,
    const float* __restrict__ Bp, const float* __restrict__ Cp,
    unsigned short* __restrict__ Vt, unsigned short* __restrict__ Mt,
    float* __restrict__ kct)
{
    const int h = blockIdx.x >> 3, dg = blockIdx.x & 7;
    const int tid = threadIdx.x, wv = tid >> 6, l = tid & 63;
    const int m = l & 31;
    const int d = (dg * 4 + wv) * 2 + (l >> 5);

    float adr, adi, bpr, bpi;
    coef1(log_dt, A_log, A_imag, Bp, Cp, h, m, adr, adi, bpr, bpi);

    float Pr = 1.f, Pi = 0.f, Qr = adr, Qi = adi;
    #pragma unroll
    for (int bit = 0; bit < 6; ++bit) {
        if ((d >> bit) & 1) { float t = Pr*Qr - Pi*Qi; Pi = Pr*Qi + Pi*Qr; Pr = t; }
        float tq = Qr*Qr - Qi*Qi; Qi = 2.f*Qr*Qi; Qr = tq;
    }
    const float wr  = Pr*bpr - Pi*bpi, wi  = Pr*bpi + Pi*bpr;   // A^d B'
    const float apr = Pr*adr - Pi*adi, api = Pr*adi + Pi*adr;   // A^{d+1}

    const size_t hb = (size_t)h * 64;
    Vt[(hb + m)      * 64 + (63 - d)] = bf16of(wr);
    Vt[(hb + 32 + m) * 64 + (63 - d)] = bf16of(wi);
    Mt[(hb + d) * 64 + m]       = bf16of(apr);
    Mt[(hb + d) * 64 + 32 + m]  = bf16of(-api);

    float s = sum32_to16(wr);
    if ((l & 31) == 16) kct[hb + d] = s + (d == 0 ? Dp[h] : 0.f);
}

// ---- shared staging: u tile (1024 t x 16 ch) -> frag-ordered bf16 LDS ----
__device__ __forceinline__ void stage_frag_u(
    const float* __restrict__ ug, unsigned short* __restrict__ ubuf, int tid)
{
    #pragma unroll
    for (int it = 0; it < 16; ++it) {
        const int t_l = it * 64 + (tid >> 2);
        const int c4  = (tid & 3) * 4;
        const float4 g = *(const float4*)(ug + (size_t)t_l * HIDDEN + c4);
        const int n = t_l >> 6, rr = t_l & 63, ksw = rr >> 5, r5 = rr & 31;
        const int lane = (r5 >> 3) * 16 + n, j = r5 & 7;
        const int base = (ksw * 64 + lane) * 8 + j;
        ubuf[(c4 + 0) * 1024 + base] = bf16of(g.x);
        ubuf[(c4 + 1) * 1024 + base] = bf16of(g.y);
        ubuf[(c4 + 2) * 1024 + base] = bf16of(g.z);
        ubuf[(c4 + 3) * 1024 + base] = bf16of(g.w);
    }
    __syncthreads();
}

// ---- Kernel 1: local chunk end states, Xend = V x U (MFMA, 16 cols) ------
__global__ __launch_bounds__(256) void ssm_states(
    const float* __restrict__ input, const unsigned short* __restrict__ Vt,
    unsigned short* __restrict__ stb)
{
    __shared__ __align__(16) unsigned short ubuf[CHB * 1024];
    const int tid = threadIdx.x, wv = tid >> 6, l = tid & 63;
    const int chb = blockIdx.x >> 1, cg = blockIdx.x & 1;
    const int chbase = chb * CHB;
    const int b = chbase >> 10, h0 = chbase & (HIDDEN - 1);
    const int lr = l & 15, lk8 = ((l >> 4) & 3) * 8, lo = (l >> 4) * 4;

    stage_frag_u(input + ((size_t)b * SEQLEN + cg * TPG) * HIDDEN + h0, ubuf, tid);

    #pragma unroll 1
    for (int c = 0; c < 4; ++c) {
        const int chl = wv * 4 + c, ch = chbase + chl, h = h0 + chl;
        Frag UB[2];
        UB[0].s = *(const s8v*)(ubuf + chl * 1024 + l * 8);
        UB[1].s = *(const s8v*)(ubuf + chl * 1024 + (64 + l) * 8);

        f32x4 acc[4];
        #pragma unroll
        for (int mt = 0; mt < 4; ++mt) { f32x4 z = {0.f,0.f,0.f,0.f}; acc[mt] = z; }

        const unsigned short* Vh = Vt + (size_t)h * 64 * 64;
        #pragma unroll
        for (int ks = 0; ks < 2; ++ks) {
            #pragma unroll
            for (int mt = 0; mt < 4; ++mt) {
                Frag VA; VA.s = *(const s8v*)(Vh + (16 * mt + lr) * 64 + ks * 32 + lk8);
                acc[mt] = __builtin_amdgcn_mfma_f32_16x16x32_bf16(
                    VA.s, UB[ks].s, acc[mt], 0, 0, 0);
            }
        }

        const int gslot = cg * 16 + lr;          // all 16 columns used
        if (gslot < NST) {
            unsigned short* sp = stb + ((size_t)ch * NST + gslot) * 64;
            #pragma unroll
            for (int mt = 0; mt < 4; ++mt) {
                uint2 w;
                w.x = cvt_pk_bf16(acc[mt][0], acc[mt][1]);
                w.y = cvt_pk_bf16(acc[mt][2], acc[mt][3]);
                *(uint2*)(sp + 16 * mt + lo) = w;
            }
        }
    }
}

// ---- Kernel 2 (tiny): in-place serial prefix over bf16 chunk states ------
__global__ void ssm_combine(
    const float* __restrict__ log_dt, const float* __restrict__ A_log,
    const float* __restrict__ A_imag, unsigned short* __restrict__ stb)
{
    const int gid = blockIdx.x * 256 + threadIdx.x;
    const int ch = gid >> 2, ll = gid & 3;
    const int h = ch & (HIDDEN - 1), m0 = ll * 8;

    f2 Pr[4], Pi[4], nPi[4];
    {
        float adr[8], adi[8];
        const float dt = expf(log_dt[h]);
        #pragma unroll
        for (int k = 0; k < 8; ++k) {
            const int idx = h * NMODES + m0 + k;
            const float hd = 0.5f * dt;
            const float ar = -expf(A_log[idx]), ai = A_imag[idx];
            const float dr = 1.f - hd * ar, di = -hd * ai;
            const float inv = 1.f / (dr * dr + di * di);
            const float nr = 1.f + hd * ar, ni = hd * ai;
            adr[k] = (nr * dr + ni * di) * inv;
            adi[k] = (ni * dr - nr * di) * inv;
        }
        #pragma unroll
        for (int p = 0; p < 4; ++p) { Pr[p] = f2{adr[2*p], adr[2*p+1]}; Pi[p] = f2{adi[2*p], adi[2*p+1]}; }
        #pragma unroll
        for (int s = 0; s < 6; ++s)
            #pragma unroll
            for (int p = 0; p < 4; ++p) {
                f2 npr = Pr[p]*Pr[p] - Pi[p]*Pi[p];
                f2 npi = Pr[p]*Pi[p]; npi = npi + npi;
                Pr[p] = npr; Pi[p] = npi;
            }
        #pragma unroll
        for (int p = 0; p < 4; ++p) nPi[p] = f2{-Pi[p].x, -Pi[p].y};
    }

    unsigned short* spb = stb + (size_t)ch * NST * 64;

    f2 Xr[4], Xi[4];
    {
        s8v vr_ = *(const s8v*)(spb + m0);
        s8v vi_ = *(const s8v*)(spb + 32 + m0);
        #pragma unroll
        for (int k = 0; k < 4; ++k) {
            Xr[k] = f2{bf2f((unsigned short)vr_[2*k]), bf2f((unsigned short)vr_[2*k+1])};
            Xi[k] = f2{bf2f((unsigned short)vi_[2*k]), bf2f((unsigned short)vi_[2*k+1])};
        }
    }

    for (int c = 1; c < NST; ++c) {
        unsigned short* sp = spb + (size_t)c * 64;
        s8v vr_ = *(const s8v*)(sp + m0);
        s8v vi_ = *(const s8v*)(sp + 32 + m0);
        #pragma unroll
        for (int p = 0; p < 4; ++p) {
            f2 sr = f2{bf2f((unsigned short)vr_[2*p]), bf2f((unsigned short)vr_[2*p+1])};
            f2 si = f2{bf2f((unsigned short)vi_[2*p]), bf2f((unsigned short)vi_[2*p+1])};
            f2 nr = pk_fma(Pr[p], Xr[p], pk_fma(nPi[p], Xi[p], sr));
            f2 ni = pk_fma(Pi[p], Xr[p], pk_fma(Pr[p], Xi[p], si));
            Xr[p] = nr; Xi[p] = ni;
        }
        uint4 wr, wi;
        wr.x = cvt_pk_bf16(Xr[0].x, Xr[0].y); wr.y = cvt_pk_bf16(Xr[1].x, Xr[1].y);
        wr.z = cvt_pk_bf16(Xr[2].x, Xr[2].y); wr.w = cvt_pk_bf16(Xr[3].x, Xr[3].y);
        wi.x = cvt_pk_bf16(Xi[0].x, Xi[0].y); wi.y = cvt_pk_bf16(Xi[1].x, Xi[1].y);
        wi.z = cvt_pk_bf16(Xi[2].x, Xi[2].y); wi.w = cvt_pk_bf16(Xi[3].x, Xi[3].y);
        *(uint4*)(sp + m0)      = wr;
        *(uint4*)(sp + 32 + m0) = wi;
    }
}

// ---- Kernel 3: Y = T x U + M x X (MFMA, 16 cols), two-half LDS flush -----
__global__ __launch_bounds__(256) void ssm_out(
    const float* __restrict__ input, const unsigned short* __restrict__ Mt,
    const float* __restrict__ kct, const unsigned short* __restrict__ stb,
    float* __restrict__ out)
{
    __shared__ __align__(16) unsigned short ubuf[CHB * 1024];  // u frags, then y tile
    __shared__ float kcP[CHB][128];   // reversed kc, zero-padded (d<0 -> 0)
    const int tid = threadIdx.x, wv = tid >> 6, l = tid & 63;
    const int chb = blockIdx.x >> 1, cg = blockIdx.x & 1;
    const int chbase = chb * CHB;
    const int b = chbase >> 10, h0 = chbase & (HIDDEN - 1);
    const int lr = l & 15, lk8 = ((l >> 4) & 3) * 8, lo = (l >> 4) * 4;

    #pragma unroll
    for (int q = 0; q < 8; ++q) {
        const int idx = q * 256 + tid, chl = idx >> 7, k = idx & 127;
        kcP[chl][k] = (k < 64) ? kct[(size_t)(h0 + chl) * 64 + (63 - k)] : 0.f;
    }
    stage_frag_u(input + ((size_t)b * SEQLEN + cg * TPG) * HIDDEN + h0, ubuf, tid);

    f32x4 acc[4][4];
    #pragma unroll
    for (int c = 0; c < 4; ++c) {
        const int chl = wv * 4 + c, ch = chbase + chl, h = h0 + chl;
        Frag UB[2];
        UB[0].s = *(const s8v*)(ubuf + chl * 1024 + l * 8);
        UB[1].s = *(const s8v*)(ubuf + chl * 1024 + (64 + l) * 8);

        #pragma unroll
        for (int mt = 0; mt < 4; ++mt) { f32x4 z = {0.f,0.f,0.f,0.f}; acc[c][mt] = z; }

        // T x U
        #pragma unroll
        for (int ks = 0; ks < 2; ++ks) {
            #pragma unroll
            for (int mt = 0; mt < 4; ++mt) {
                const int base = 63 - 16 * mt + 32 * ks + lk8 - lr;
                float f[8];
                #pragma unroll
                for (int j = 0; j < 8; ++j) f[j] = kcP[chl][base + j];
                Frag TA;
                #pragma unroll
                for (int q = 0; q < 4; ++q) TA.u[q] = cvt_pk_bf16(f[2*q], f[2*q+1]);
                acc[c][mt] = __builtin_amdgcn_mfma_f32_16x16x32_bf16(
                    TA.s, UB[ks].s, acc[c][mt], 0, 0, 0);
            }
        }

        // M x X (all 16 columns now)
        const int gc = cg * 16 + lr;
        const bool xv = (gc > 0);
        Frag XB[2];
        #pragma unroll
        for (int ks = 0; ks < 2; ++ks) {
            if (xv) XB[ks].s = *(const s8v*)(stb + ((size_t)ch * NST + gc - 1) * 64 + ks * 32 + lk8);
            else { XB[ks].u[0] = XB[ks].u[1] = XB[ks].u[2] = XB[ks].u[3] = 0; }
        }
        const unsigned short* Mh = Mt + (size_t)h * 64 * 64;
        #pragma unroll
        for (int ks = 0; ks < 2; ++ks) {
            #pragma unroll
            for (int mt = 0; mt < 4; ++mt) {
                Frag MA; MA.s = *(const s8v*)(Mh + (16 * mt + lr) * 64 + ks * 32 + lk8);
                acc[c][mt] = __builtin_amdgcn_mfma_f32_16x16x32_bf16(
                    MA.s, XB[ks].s, acc[c][mt], 0, 0, 0);
            }
        }
    }

    // two-half flush through the (verified) swizzled [512][32] y tile
    float* ob = out + ((size_t)b * SEQLEN + cg * TPG) * HIDDEN + h0;
    #pragma unroll
    for (int half = 0; half < 2; ++half) {
        __syncthreads();   // ubuf (u) / previous tile reads done
        if ((lr >> 3) == half) {
            const int lr7 = lr & 7;
            #pragma unroll
            for (int c = 0; c < 4; ++c) {
                const int chl = wv * 4 + c;
                const int col = chl ^ (lr7 << 1);
                #pragma unroll
                for (int mt = 0; mt < 4; ++mt)
                    #pragma unroll
                    for (int r = 0; r < 4; ++r) {
                        const int t_loc = lr7 * 64 + 16 * mt + lo + r;
                        ubuf[t_loc * 32 + col] = bf16of(acc[c][mt][r]);
                    }
            }
        }
        __syncthreads();
        float* obh = ob + (size_t)half * 512 * HIDDEN;
        #pragma unroll
        for (int q = 0; q < 8; ++q) {
            const int idx = q * 256 + tid;
            const int t_loc = idx >> 2, a = idx & 3;
            const int lrt = (t_loc >> 6) & 7;
            const int blk = (a ^ (lrt >> 1)) * 4;
            const uint2 w = *(const uint2*)(ubuf + t_loc * 32 + blk);
            const float s0 = bf2f(w.x & 0xffffu), s1 = bf2f(w.x >> 16);
            const float s2 = bf2f(w.y & 0xffffu), s3 = bf2f(w.y >> 16);
            float4 o;
            if (lrt & 1) o = make_float4(s2, s3, s0, s1);
            else         o = make_float4(s0, s1, s2, s3);
            *(float4*)(obh + (size_t)t_loc * HIDDEN + a * 4) = o;
        }
    }
}

extern "C" void kernel_launch(void* const* d_in, const int* in_sizes, int n_in,
                              void* d_out, int out_size, void* d_ws, size_t ws_size,
                              hipStream_t stream) {
    const float* input  = (const float*)d_in[0];
    const float* log_dt = (const float*)d_in[1];
    const float* Dp     = (const float*)d_in[2];
    const float* A_log  = (const float*)d_in[3];
    const float* A_imag = (const float*)d_in[4];
    const float* Bp     = (const float*)d_in[5];
    const float* Cp     = (const float*)d_in[6];
    float* out = (float*)d_out;

    unsigned short* Vt  = (unsigned short*)d_ws;
    unsigned short* Mtb = (unsigned short*)((char*)d_ws + OFF_M);
    float*          kct = (float*)((char*)d_ws + OFF_K);
    unsigned short* stb = (unsigned short*)((char*)d_ws + OFF_S);

    ssm_tables<<<dim3(1024 * 8), dim3(256), 0, stream>>>(
        log_dt, Dp, A_log, A_imag, Bp, Cp, Vt, Mtb, kct);
    ssm_states<<<dim3((CHANNELS / CHB) * NGC), dim3(256), 0, stream>>>(
        input, Vt, stb);
    ssm_combine<<<dim3(CHANNELS * 4 / 256), dim3(256), 0, stream>>>(
        log_dt, A_log, A_imag, stb);
    ssm_out<<<dim3((CHANNELS / CHB) * NGC), dim3(256), 0, stream>>>(
        input, Mtb, kct, stb, out);
}